// Round 15
// baseline (274.702 us; speedup 1.0000x reference)
//
#include <hip/hip_runtime.h>
#include <hip/hip_bf16.h>

#define M_ROWS 16384
#define N_IN   512
#define N_HID  1024
#define K_TOT  1536   // 512 + 1024
#define N_TOT  4096   // 4 gates * 1024
#define NT     48     // K tiles of BK=32

typedef __attribute__((ext_vector_type(4))) float f32x4;
typedef __attribute__((ext_vector_type(8))) short bf16x8;
typedef __attribute__((ext_vector_type(4))) int   i32x4;

__device__ __forceinline__ ushort f2bf(float f) {
    union { float f; unsigned u; } un; un.f = f;
    unsigned u = un.u;
    u += 0x7fffu + ((u >> 16) & 1u);   // RNE
    return (ushort)(u >> 16);
}

__device__ __forceinline__ bf16x8 as_bf(i32x4 v) {
    union { i32x4 i; bf16x8 b; } u; u.i = v; return u.b;
}

// ---------------- fused prep kernel (R12, validated) ----------------

__global__ void prep_all(const float* __restrict__ x, const float* __restrict__ h,
                         const float* __restrict__ Wii, const float* __restrict__ Wif,
                         const float* __restrict__ Wig, const float* __restrict__ Wio,
                         const float* __restrict__ Whi, const float* __restrict__ Whf,
                         const float* __restrict__ Whg, const float* __restrict__ Who,
                         const float* __restrict__ bii, const float* __restrict__ bif,
                         const float* __restrict__ big, const float* __restrict__ bio,
                         const float* __restrict__ bhi, const float* __restrict__ bhf,
                         const float* __restrict__ bhg, const float* __restrict__ bho,
                         ushort* __restrict__ A, ushort* __restrict__ Wp,
                         float* __restrict__ bias) {
    const int totalA = M_ROWS * K_TOT / 4;   // 6,291,456
    const int totalW = N_TOT * K_TOT / 4;    // 1,572,864
    const int totalE = totalA + totalW + N_TOT;
    const int stride = gridDim.x * blockDim.x;
    for (int p = blockIdx.x * blockDim.x + threadIdx.x; p < totalE; p += stride) {
        if (p < totalA) {
            int flat = p * 4;
            int row = flat / K_TOT;
            int col = flat - row * K_TOT;
            const float* src = (col < N_IN)
                ? (x + (size_t)row * N_IN + col)
                : (h + (size_t)row * N_HID + (col - N_IN));
            float4 v = *(const float4*)src;
            ushort4 o;
            o.x = f2bf(v.x); o.y = f2bf(v.y); o.z = f2bf(v.z); o.w = f2bf(v.w);
            *(ushort4*)(A + flat) = o;
        } else if (p < totalA + totalW) {
            int q = p - totalA;
            int flat = q * 4;
            int prow = flat / K_TOT;
            int col = flat - prow * K_TOT;
            int bn  = prow >> 8;
            int r   = prow & 255;
            int wcn = r >> 6;
            int g   = (r >> 4) & 3;
            int u   = r & 15;
            int j   = bn * 64 + wcn * 16 + u;
            const float* src;
            if (col < N_IN) {
                const float* Wx = (g == 0) ? Wii : (g == 1) ? Wif : (g == 2) ? Wig : Wio;
                src = Wx + (size_t)j * N_IN + col;
            } else {
                const float* Wh = (g == 0) ? Whi : (g == 1) ? Whf : (g == 2) ? Whg : Who;
                src = Wh + (size_t)j * N_HID + (col - N_IN);
            }
            float4 v = *(const float4*)src;
            ushort4 o;
            o.x = f2bf(v.x); o.y = f2bf(v.y); o.z = f2bf(v.z); o.w = f2bf(v.w);
            *(ushort4*)(Wp + flat) = o;
        } else {
            int n = p - totalA - totalW;
            int g = n >> 10, j = n & 1023;
            const float* bx = (g == 0) ? bii : (g == 1) ? bif : (g == 2) ? big : bio;
            const float* bh = (g == 0) ? bhi : (g == 1) ? bhf : (g == 2) ? bhg : bho;
            bias[n] = bx[j] + bh[j];
        }
    }
}

// ---------------- rotated-pipeline GEMM + LSTM epilogue (R13, verified) ---
// 256x256 block, BK=32, 48 K-tiles, 8 waves (2M x 4N), per-wave 128x64.
// 4 LDS buffers; register rotate (frags for t+1 ds_read during t, asm
// ds_read_b128 + counted lgkmcnt(12)); intrinsic global_load_lds staging,
// stage-ahead-3, VMC(4) retires buf(t+2) one tile before its reads.
// Grid: plain 2D. R14's persistent-block variant NaN'd (suspected
// spill-after-asm-ds_read under unrolled-loop pressure) — reverted.

__device__ __forceinline__ float sigmoid_f(float z) {
    return 1.f / (1.f + __expf(-z));
}
__device__ __forceinline__ float tanh_f(float z) {
    z = fminf(fmaxf(z, -15.f), 15.f);
    float e = __expf(2.f * z);
    return (e - 1.f) / (e + 1.f);
}

__global__ __launch_bounds__(512, 1) void lstm_gemm(
        const ushort* __restrict__ A, const ushort* __restrict__ W,
        const float* __restrict__ bias, const float* __restrict__ cin,
        float* __restrict__ outc, float* __restrict__ outh) {
    __shared__ ushort sA[4][256 * 32];   // 4 x 16 KB
    __shared__ ushort sB[4][256 * 32];   // 4 x 16 KB  (128 KB total)

    const int tid  = threadIdx.x;
    const int wid  = tid >> 6;
    const int lane = tid & 63;
    const int wr  = wid >> 2;    // 0..1  M half
    const int wcn = wid & 3;     // 0..3  N quarter (64 cols)
    const int m0 = blockIdx.x * 256;
    const int n0 = blockIdx.y * 256;

    f32x4 acc[8][4] = {};

    // staging map (validated): row = tid>>2, global chunk = (tid&3)^((tid>>3)&3)
    const int srow = tid >> 2;
    const int fch  = (tid & 3) ^ ((tid >> 3) & 3);
    const ushort* gA = A + (size_t)(m0 + srow) * K_TOT + fch * 8;
    const ushort* gB = W + (size_t)(n0 + srow) * K_TOT + fch * 8;

#define GLDS(gptr, lptr) __builtin_amdgcn_global_load_lds(                     \
        (const __attribute__((address_space(1))) void*)(gptr),                 \
        (__attribute__((address_space(3))) void*)(lptr), 16, 0, 0)

#define STAGE(db, kt) do {                                                     \
    GLDS(gA + (size_t)(kt) * 32,                  &sA[db][tid * 8]);           \
    GLDS(gA + (size_t)128 * K_TOT + (size_t)(kt) * 32, &sA[db][4096 + tid * 8]); \
    GLDS(gB + (size_t)(kt) * 32,                  &sB[db][tid * 8]);           \
    GLDS(gB + (size_t)128 * K_TOT + (size_t)(kt) * 32, &sB[db][4096 + tid * 8]); \
} while (0)

    const int lrow = lane & 15;
    const int cb0  = lane >> 4;             // 0..3 k-chunk
    const int csw2 = (lrow >> 1) & 3;       // read-side swizzle (0-conflict)
    const unsigned aByte = (unsigned)(((wr * 128 + lrow) * 32 + ((cb0 ^ csw2) * 8)) * 2);
    const unsigned bByte = (unsigned)(((wcn * 64  + lrow) * 32 + ((cb0 ^ csw2) * 8)) * 2);

#define DSR(dst, addr, IMM) asm volatile(                                      \
    "ds_read_b128 %0, %1 offset:" IMM : "=&v"(dst) : "v"(addr))

#define READS(afX, bfX, db) do {                                               \
    unsigned aAd = (unsigned)(uintptr_t)                                       \
        (__attribute__((address_space(3))) ushort*)&sA[db][0] + aByte;         \
    unsigned bAd = (unsigned)(uintptr_t)                                       \
        (__attribute__((address_space(3))) ushort*)&sB[db][0] + bByte;         \
    i32x4 r0, r1, r2, r3, r4, r5, r6, r7, s0, s1, s2, s3;                      \
    DSR(r0, aAd, "0");    DSR(r1, aAd, "1024");                                \
    DSR(r2, aAd, "2048"); DSR(r3, aAd, "3072");                                \
    DSR(r4, aAd, "4096"); DSR(r5, aAd, "5120");                                \
    DSR(r6, aAd, "6144"); DSR(r7, aAd, "7168");                                \
    DSR(s0, bAd, "0");    DSR(s1, bAd, "1024");                                \
    DSR(s2, bAd, "2048"); DSR(s3, bAd, "3072");                                \
    afX[0] = as_bf(r0); afX[1] = as_bf(r1); afX[2] = as_bf(r2);                \
    afX[3] = as_bf(r3); afX[4] = as_bf(r4); afX[5] = as_bf(r5);                \
    afX[6] = as_bf(r6); afX[7] = as_bf(r7);                                    \
    bfX[0] = as_bf(s0); bfX[1] = as_bf(s1); bfX[2] = as_bf(s2);                \
    bfX[3] = as_bf(s3);                                                        \
} while (0)

#define WAITK(n) do {                                                          \
    asm volatile("s_waitcnt lgkmcnt(" #n ")");                                 \
    __builtin_amdgcn_sched_barrier(0);                                         \
} while (0)

#define MFMAS(afX, bfX) do {                                                   \
    __builtin_amdgcn_s_setprio(1);                                             \
    _Pragma("unroll")                                                          \
    for (int m = 0; m < 8; ++m)                                                \
        _Pragma("unroll")                                                      \
        for (int n = 0; n < 4; ++n)                                            \
            acc[m][n] = __builtin_amdgcn_mfma_f32_16x16x32_bf16(               \
                afX[m], bfX[n], acc[m][n], 0, 0, 0);                           \
    __builtin_amdgcn_s_setprio(0);                                             \
} while (0)

#define BARX() __builtin_amdgcn_s_barrier()
#define VMC(n) asm volatile("s_waitcnt vmcnt(" #n ")" ::: "memory")

    bf16x8 af0[8], bfv0[4], af1[8], bfv1[4];

    // prologue: stage tiles 0,1,2; retire 0,1; read tile-0 frags
    STAGE(0, 0); STAGE(1, 1); STAGE(2, 2);
    VMC(4);
    BARX();
    READS(af0, bfv0, 0);

    // tile t: STAGE(t+3) | READS(t+1) | lgkm(12) | MFMA(t) | VMC(4) | BAR
#define TILE(u, t, Fna, Fnb, Fca, Fcb) do {                                    \
    STAGE(((u) + 3) & 3, (t) + 3);                                             \
    READS(Fna, Fnb, ((u) + 1) & 3);                                            \
    WAITK(12);                                                                 \
    MFMAS(Fca, Fcb);                                                           \
    VMC(4);                                                                    \
    BARX();                                                                    \
} while (0)

    for (int hh = 0; hh < 11; ++hh) {
        const int t = hh * 4;
        TILE(0, t + 0, af1, bfv1, af0, bfv0);
        TILE(1, t + 1, af0, bfv0, af1, bfv1);
        TILE(2, t + 2, af1, bfv1, af0, bfv0);
        TILE(3, t + 3, af0, bfv0, af1, bfv1);
    }
    // peeled tail: t = 44..47
    TILE(0, 44, af1, bfv1, af0, bfv0);          // stages 47
    // t=45: no stage; VMC(0) retires S47 before t=46 reads buf3
    READS(af0, bfv0, 2);                        // tile 46 frags
    WAITK(12);
    MFMAS(af1, bfv1);                           // tile 45
    VMC(0);
    BARX();
    // t=46
    READS(af1, bfv1, 3);                        // tile 47 frags
    WAITK(12);
    MFMAS(af0, bfv0);                           // tile 46
    BARX();
    // t=47
    WAITK(0);
    MFMAS(af1, bfv1);                           // tile 47

    // epilogue: lane owns unit = bn*64 + wcn*16 + lrow; gates = acc[m][0..3]
    const int unit = blockIdx.y * 64 + wcn * 16 + lrow;
    const float b0 = bias[unit];
    const float b1 = bias[1024 + unit];
    const float b2 = bias[2048 + unit];
    const float b3 = bias[3072 + unit];
    const int r0 = m0 + wr * 128 + (lane >> 4) * 4;
#pragma unroll
    for (int mi = 0; mi < 8; ++mi) {
#pragma unroll
        for (int q = 0; q < 4; ++q) {
            const int row = r0 + mi * 16 + q;
            const size_t off = (size_t)row * N_HID + unit;
            float zi = acc[mi][0][q] + b0;
            float zf = acc[mi][1][q] + b1;
            float zg = acc[mi][2][q] + b2;
            float zo = acc[mi][3][q] + b3;
            float it_ = sigmoid_f(zi);
            float ft = sigmoid_f(zf);
            float gt = tanh_f(zg);
            float ot = sigmoid_f(zo);
            float ct = ft * cin[off] + it_ * gt;
            float ht = ot * tanh_f(ct);
            outc[off] = ct;
            outh[off] = ht;
        }
    }
#undef GLDS
#undef STAGE
#undef DSR
#undef READS
#undef WAITK
#undef MFMAS
#undef BARX
#undef VMC
#undef TILE
}

// ---------------- launch ----------------

extern "C" void kernel_launch(void* const* d_in, const int* in_sizes, int n_in,
                              void* d_out, int out_size, void* d_ws, size_t ws_size,
                              hipStream_t stream) {
    const float* x = (const float*)d_in[0];
    const float* c = (const float*)d_in[1];
    const float* h = (const float*)d_in[2];
    const float* Wii = (const float*)d_in[3];  const float* bii = (const float*)d_in[4];
    const float* Wif = (const float*)d_in[5];  const float* bif = (const float*)d_in[6];
    const float* Wig = (const float*)d_in[7];  const float* big = (const float*)d_in[8];
    const float* Wio = (const float*)d_in[9];  const float* bio = (const float*)d_in[10];
    const float* Whi = (const float*)d_in[11]; const float* bhi = (const float*)d_in[12];
    const float* Whf = (const float*)d_in[13]; const float* bhf = (const float*)d_in[14];
    const float* Whg = (const float*)d_in[15]; const float* bhg = (const float*)d_in[16];
    const float* Who = (const float*)d_in[17]; const float* bho = (const float*)d_in[18];

    char* ws = (char*)d_ws;
    ushort* A_cat  = (ushort*)ws;                                   // 50,331,648 B
    ushort* W_perm = (ushort*)(ws + (size_t)M_ROWS * K_TOT * 2);    // 12,582,912 B
    float*  biasc  = (float*)(ws + (size_t)M_ROWS * K_TOT * 2
                                 + (size_t)N_TOT * K_TOT * 2);      // 16 KB

    float* outc = (float*)d_out;
    float* outh = (float*)d_out + (size_t)M_ROWS * N_HID;

    hipLaunchKernelGGL(prep_all, dim3(2048), dim3(256), 0, stream,
                       x, h,
                       Wii, Wif, Wig, Wio, Whi, Whf, Whg, Who,
                       bii, bif, big, bio, bhi, bhf, bhg, bho,
                       A_cat, W_perm, biasc);
    hipLaunchKernelGGL(lstm_gemm, dim3(M_ROWS / 256, N_TOT / 256), dim3(512), 0, stream,
                       A_cat, W_perm, biasc, c, outc, outh);
}

// Round 17
// 273.767 us; speedup vs baseline: 1.0034x; 1.0034x over previous
//
#include <hip/hip_runtime.h>
#include <hip/hip_bf16.h>

#define M_ROWS 16384
#define N_IN   512
#define N_HID  1024
#define K_TOT  1536   // 512 + 1024
#define N_TOT  4096   // 4 gates * 1024
#define NT     48     // K tiles of BK=32

typedef __attribute__((ext_vector_type(4))) float f32x4;
typedef __attribute__((ext_vector_type(8))) short bf16x8;
typedef __attribute__((ext_vector_type(4))) int   i32x4;

__device__ __forceinline__ ushort f2bf(float f) {
    union { float f; unsigned u; } un; un.f = f;
    unsigned u = un.u;
    u += 0x7fffu + ((u >> 16) & 1u);   // RNE
    return (ushort)(u >> 16);
}

__device__ __forceinline__ bf16x8 as_bf(i32x4 v) {
    union { i32x4 i; bf16x8 b; } u; u.i = v; return u.b;
}

// ---------------- fused prep kernel (R12, validated) ----------------

__global__ void prep_all(const float* __restrict__ x, const float* __restrict__ h,
                         const float* __restrict__ Wii, const float* __restrict__ Wif,
                         const float* __restrict__ Wig, const float* __restrict__ Wio,
                         const float* __restrict__ Whi, const float* __restrict__ Whf,
                         const float* __restrict__ Whg, const float* __restrict__ Who,
                         const float* __restrict__ bii, const float* __restrict__ bif,
                         const float* __restrict__ big, const float* __restrict__ bio,
                         const float* __restrict__ bhi, const float* __restrict__ bhf,
                         const float* __restrict__ bhg, const float* __restrict__ bho,
                         ushort* __restrict__ A, ushort* __restrict__ Wp,
                         float* __restrict__ bias) {
    const int totalA = M_ROWS * K_TOT / 4;   // 6,291,456
    const int totalW = N_TOT * K_TOT / 4;    // 1,572,864
    const int totalE = totalA + totalW + N_TOT;
    const int stride = gridDim.x * blockDim.x;
    for (int p = blockIdx.x * blockDim.x + threadIdx.x; p < totalE; p += stride) {
        if (p < totalA) {
            int flat = p * 4;
            int row = flat / K_TOT;
            int col = flat - row * K_TOT;
            const float* src = (col < N_IN)
                ? (x + (size_t)row * N_IN + col)
                : (h + (size_t)row * N_HID + (col - N_IN));
            float4 v = *(const float4*)src;
            ushort4 o;
            o.x = f2bf(v.x); o.y = f2bf(v.y); o.z = f2bf(v.z); o.w = f2bf(v.w);
            *(ushort4*)(A + flat) = o;
        } else if (p < totalA + totalW) {
            int q = p - totalA;
            int flat = q * 4;
            int prow = flat / K_TOT;
            int col = flat - prow * K_TOT;
            int bn  = prow >> 8;
            int r   = prow & 255;
            int wcn = r >> 6;
            int g   = (r >> 4) & 3;
            int u   = r & 15;
            int j   = bn * 64 + wcn * 16 + u;
            const float* src;
            if (col < N_IN) {
                const float* Wx = (g == 0) ? Wii : (g == 1) ? Wif : (g == 2) ? Wig : Wio;
                src = Wx + (size_t)j * N_IN + col;
            } else {
                const float* Wh = (g == 0) ? Whi : (g == 1) ? Whf : (g == 2) ? Whg : Who;
                src = Wh + (size_t)j * N_HID + (col - N_IN);
            }
            float4 v = *(const float4*)src;
            ushort4 o;
            o.x = f2bf(v.x); o.y = f2bf(v.y); o.z = f2bf(v.z); o.w = f2bf(v.w);
            *(ushort4*)(Wp + flat) = o;
        } else {
            int n = p - totalA - totalW;
            int g = n >> 10, j = n & 1023;
            const float* bx = (g == 0) ? bii : (g == 1) ? bif : (g == 2) ? big : bio;
            const float* bh = (g == 0) ? bhi : (g == 1) ? bhf : (g == 2) ? bhg : bho;
            bias[n] = bx[j] + bh[j];
        }
    }
}

// ---------------- rotated-pipeline GEMM + LSTM epilogue (R13, verified) ---
// 256x256 block, BK=32, 48 K-tiles, 8 waves (2M x 4N), per-wave 128x64.
// 4 LDS buffers; register rotate (frags for t+1 ds_read during t, asm
// ds_read_b128 + counted lgkmcnt(12)); intrinsic global_load_lds staging,
// stage-ahead-3, VMC(4) retires buf(t+2) one tile before its reads.
// Session map: 9 schedule structures all land 744-831 TF / 33-37% MfmaUtil
// (the documented 2-phase-class plateau); 2-block/CU at 256-tile is
// register-infeasible (acc=128 f32/wave); 128-tile co-residency loses on
// L2 traffic. This is the best verified composition (270.5/274.7 us).

__device__ __forceinline__ float sigmoid_f(float z) {
    return 1.f / (1.f + __expf(-z));
}
__device__ __forceinline__ float tanh_f(float z) {
    z = fminf(fmaxf(z, -15.f), 15.f);
    float e = __expf(2.f * z);
    return (e - 1.f) / (e + 1.f);
}

__global__ __launch_bounds__(512, 1) void lstm_gemm(
        const ushort* __restrict__ A, const ushort* __restrict__ W,
        const float* __restrict__ bias, const float* __restrict__ cin,
        float* __restrict__ outc, float* __restrict__ outh) {
    __shared__ ushort sA[4][256 * 32];   // 4 x 16 KB
    __shared__ ushort sB[4][256 * 32];   // 4 x 16 KB  (128 KB total)

    const int tid  = threadIdx.x;
    const int wid  = tid >> 6;
    const int lane = tid & 63;
    const int wr  = wid >> 2;    // 0..1  M half
    const int wcn = wid & 3;     // 0..3  N quarter (64 cols)
    const int m0 = blockIdx.x * 256;
    const int n0 = blockIdx.y * 256;

    f32x4 acc[8][4] = {};

    // staging map (validated): row = tid>>2, global chunk = (tid&3)^((tid>>3)&3)
    const int srow = tid >> 2;
    const int fch  = (tid & 3) ^ ((tid >> 3) & 3);
    const ushort* gA = A + (size_t)(m0 + srow) * K_TOT + fch * 8;
    const ushort* gB = W + (size_t)(n0 + srow) * K_TOT + fch * 8;

#define GLDS(gptr, lptr) __builtin_amdgcn_global_load_lds(                     \
        (const __attribute__((address_space(1))) void*)(gptr),                 \
        (__attribute__((address_space(3))) void*)(lptr), 16, 0, 0)

#define STAGE(db, kt) do {                                                     \
    GLDS(gA + (size_t)(kt) * 32,                  &sA[db][tid * 8]);           \
    GLDS(gA + (size_t)128 * K_TOT + (size_t)(kt) * 32, &sA[db][4096 + tid * 8]); \
    GLDS(gB + (size_t)(kt) * 32,                  &sB[db][tid * 8]);           \
    GLDS(gB + (size_t)128 * K_TOT + (size_t)(kt) * 32, &sB[db][4096 + tid * 8]); \
} while (0)

    const int lrow = lane & 15;
    const int cb0  = lane >> 4;             // 0..3 k-chunk
    const int csw2 = (lrow >> 1) & 3;       // read-side swizzle (0-conflict)
    const unsigned aByte = (unsigned)(((wr * 128 + lrow) * 32 + ((cb0 ^ csw2) * 8)) * 2);
    const unsigned bByte = (unsigned)(((wcn * 64  + lrow) * 32 + ((cb0 ^ csw2) * 8)) * 2);

#define DSR(dst, addr, IMM) asm volatile(                                      \
    "ds_read_b128 %0, %1 offset:" IMM : "=&v"(dst) : "v"(addr))

#define READS(afX, bfX, db) do {                                               \
    unsigned aAd = (unsigned)(uintptr_t)                                       \
        (__attribute__((address_space(3))) ushort*)&sA[db][0] + aByte;         \
    unsigned bAd = (unsigned)(uintptr_t)                                       \
        (__attribute__((address_space(3))) ushort*)&sB[db][0] + bByte;         \
    i32x4 r0, r1, r2, r3, r4, r5, r6, r7, s0, s1, s2, s3;                      \
    DSR(r0, aAd, "0");    DSR(r1, aAd, "1024");                                \
    DSR(r2, aAd, "2048"); DSR(r3, aAd, "3072");                                \
    DSR(r4, aAd, "4096"); DSR(r5, aAd, "5120");                                \
    DSR(r6, aAd, "6144"); DSR(r7, aAd, "7168");                                \
    DSR(s0, bAd, "0");    DSR(s1, bAd, "1024");                                \
    DSR(s2, bAd, "2048"); DSR(s3, bAd, "3072");                                \
    afX[0] = as_bf(r0); afX[1] = as_bf(r1); afX[2] = as_bf(r2);                \
    afX[3] = as_bf(r3); afX[4] = as_bf(r4); afX[5] = as_bf(r5);                \
    afX[6] = as_bf(r6); afX[7] = as_bf(r7);                                    \
    bfX[0] = as_bf(s0); bfX[1] = as_bf(s1); bfX[2] = as_bf(s2);                \
    bfX[3] = as_bf(s3);                                                        \
} while (0)

#define WAITK(n) do {                                                          \
    asm volatile("s_waitcnt lgkmcnt(" #n ")");                                 \
    __builtin_amdgcn_sched_barrier(0);                                         \
} while (0)

#define MFMAS(afX, bfX) do {                                                   \
    __builtin_amdgcn_s_setprio(1);                                             \
    _Pragma("unroll")                                                          \
    for (int m = 0; m < 8; ++m)                                                \
        _Pragma("unroll")                                                      \
        for (int n = 0; n < 4; ++n)                                            \
            acc[m][n] = __builtin_amdgcn_mfma_f32_16x16x32_bf16(               \
                afX[m], bfX[n], acc[m][n], 0, 0, 0);                           \
    __builtin_amdgcn_s_setprio(0);                                             \
} while (0)

#define BARX() __builtin_amdgcn_s_barrier()
#define VMC(n) asm volatile("s_waitcnt vmcnt(" #n ")" ::: "memory")

    bf16x8 af0[8], bfv0[4], af1[8], bfv1[4];

    // prologue: stage tiles 0,1,2; retire 0,1; read tile-0 frags
    STAGE(0, 0); STAGE(1, 1); STAGE(2, 2);
    VMC(4);
    BARX();
    READS(af0, bfv0, 0);

    // tile t: STAGE(t+3) | READS(t+1) | lgkm(12) | MFMA(t) | VMC(4) | BAR
#define TILE(u, t, Fna, Fnb, Fca, Fcb) do {                                    \
    STAGE(((u) + 3) & 3, (t) + 3);                                             \
    READS(Fna, Fnb, ((u) + 1) & 3);                                            \
    WAITK(12);                                                                 \
    MFMAS(Fca, Fcb);                                                           \
    VMC(4);                                                                    \
    BARX();                                                                    \
} while (0)

    for (int hh = 0; hh < 11; ++hh) {
        const int t = hh * 4;
        TILE(0, t + 0, af1, bfv1, af0, bfv0);
        TILE(1, t + 1, af0, bfv0, af1, bfv1);
        TILE(2, t + 2, af1, bfv1, af0, bfv0);
        TILE(3, t + 3, af0, bfv0, af1, bfv1);
    }
    // peeled tail: t = 44..47
    TILE(0, 44, af1, bfv1, af0, bfv0);          // stages 47
    // t=45: no stage; VMC(0) retires S47 before t=46 reads buf3
    READS(af0, bfv0, 2);                        // tile 46 frags
    WAITK(12);
    MFMAS(af1, bfv1);                           // tile 45
    VMC(0);
    BARX();
    // t=46
    READS(af1, bfv1, 3);                        // tile 47 frags
    WAITK(12);
    MFMAS(af0, bfv0);                           // tile 46
    BARX();
    // t=47
    WAITK(0);
    MFMAS(af1, bfv1);                           // tile 47

    // epilogue: lane owns unit = bn*64 + wcn*16 + lrow; gates = acc[m][0..3]
    const int unit = blockIdx.y * 64 + wcn * 16 + lrow;
    const float b0 = bias[unit];
    const float b1 = bias[1024 + unit];
    const float b2 = bias[2048 + unit];
    const float b3 = bias[3072 + unit];
    const int r0 = m0 + wr * 128 + (lane >> 4) * 4;
#pragma unroll
    for (int mi = 0; mi < 8; ++mi) {
#pragma unroll
        for (int q = 0; q < 4; ++q) {
            const int row = r0 + mi * 16 + q;
            const size_t off = (size_t)row * N_HID + unit;
            float zi = acc[mi][0][q] + b0;
            float zf = acc[mi][1][q] + b1;
            float zg = acc[mi][2][q] + b2;
            float zo = acc[mi][3][q] + b3;
            float it_ = sigmoid_f(zi);
            float ft = sigmoid_f(zf);
            float gt = tanh_f(zg);
            float ot = sigmoid_f(zo);
            float ct = ft * cin[off] + it_ * gt;
            float ht = ot * tanh_f(ct);
            outc[off] = ct;
            outh[off] = ht;
        }
    }
#undef GLDS
#undef STAGE
#undef DSR
#undef READS
#undef WAITK
#undef MFMAS
#undef BARX
#undef VMC
#undef TILE
}

// ---------------- launch ----------------

extern "C" void kernel_launch(void* const* d_in, const int* in_sizes, int n_in,
                              void* d_out, int out_size, void* d_ws, size_t ws_size,
                              hipStream_t stream) {
    const float* x = (const float*)d_in[0];
    const float* c = (const float*)d_in[1];
    const float* h = (const float*)d_in[2];
    const float* Wii = (const float*)d_in[3];  const float* bii = (const float*)d_in[4];
    const float* Wif = (const float*)d_in[5];  const float* bif = (const float*)d_in[6];
    const float* Wig = (const float*)d_in[7];  const float* big = (const float*)d_in[8];
    const float* Wio = (const float*)d_in[9];  const float* bio = (const float*)d_in[10];
    const float* Whi = (const float*)d_in[11]; const float* bhi = (const float*)d_in[12];
    const float* Whf = (const float*)d_in[13]; const float* bhf = (const float*)d_in[14];
    const float* Whg = (const float*)d_in[15]; const float* bhg = (const float*)d_in[16];
    const float* Who = (const float*)d_in[17]; const float* bho = (const float*)d_in[18];

    char* ws = (char*)d_ws;
    ushort* A_cat  = (ushort*)ws;                                   // 50,331,648 B
    ushort* W_perm = (ushort*)(ws + (size_t)M_ROWS * K_TOT * 2);    // 12,582,912 B
    float*  biasc  = (float*)(ws + (size_t)M_ROWS * K_TOT * 2
                                 + (size_t)N_TOT * K_TOT * 2);      // 16 KB

    float* outc = (float*)d_out;
    float* outh = (float*)d_out + (size_t)M_ROWS * N_HID;

    hipLaunchKernelGGL(prep_all, dim3(2048), dim3(256), 0, stream,
                       x, h,
                       Wii, Wif, Wig, Wio, Whi, Whf, Whg, Who,
                       bii, bif, big, bio, bhi, bhf, bhg, bho,
                       A_cat, W_perm, biasc);
    hipLaunchKernelGGL(lstm_gemm, dim3(M_ROWS / 256, N_TOT / 256), dim3(512), 0, stream,
                       A_cat, W_perm, biasc, c, outc, outh);
}

// Round 18
// 271.372 us; speedup vs baseline: 1.0123x; 1.0088x over previous
//
#include <hip/hip_runtime.h>
#include <hip/hip_bf16.h>

#define M_ROWS 16384
#define N_IN   512
#define N_HID  1024
#define K_TOT  1536   // 512 + 1024
#define N_TOT  4096   // 4 gates * 1024
#define NT     48     // K tiles of BK=32

typedef __attribute__((ext_vector_type(4))) float f32x4;
typedef __attribute__((ext_vector_type(8))) short bf16x8;
typedef __attribute__((ext_vector_type(4))) int   i32x4;

__device__ __forceinline__ ushort f2bf(float f) {
    union { float f; unsigned u; } un; un.f = f;
    unsigned u = un.u;
    u += 0x7fffu + ((u >> 16) & 1u);   // RNE
    return (ushort)(u >> 16);
}

__device__ __forceinline__ bf16x8 as_bf(i32x4 v) {
    union { i32x4 i; bf16x8 b; } u; u.i = v; return u.b;
}

// ---------------- fused prep kernel (R12, validated) ----------------

__global__ void prep_all(const float* __restrict__ x, const float* __restrict__ h,
                         const float* __restrict__ Wii, const float* __restrict__ Wif,
                         const float* __restrict__ Wig, const float* __restrict__ Wio,
                         const float* __restrict__ Whi, const float* __restrict__ Whf,
                         const float* __restrict__ Whg, const float* __restrict__ Who,
                         const float* __restrict__ bii, const float* __restrict__ bif,
                         const float* __restrict__ big, const float* __restrict__ bio,
                         const float* __restrict__ bhi, const float* __restrict__ bhf,
                         const float* __restrict__ bhg, const float* __restrict__ bho,
                         ushort* __restrict__ A, ushort* __restrict__ Wp,
                         float* __restrict__ bias) {
    const int totalA = M_ROWS * K_TOT / 4;   // 6,291,456
    const int totalW = N_TOT * K_TOT / 4;    // 1,572,864
    const int totalE = totalA + totalW + N_TOT;
    const int stride = gridDim.x * blockDim.x;
    for (int p = blockIdx.x * blockDim.x + threadIdx.x; p < totalE; p += stride) {
        if (p < totalA) {
            int flat = p * 4;
            int row = flat / K_TOT;
            int col = flat - row * K_TOT;
            const float* src = (col < N_IN)
                ? (x + (size_t)row * N_IN + col)
                : (h + (size_t)row * N_HID + (col - N_IN));
            float4 v = *(const float4*)src;
            ushort4 o;
            o.x = f2bf(v.x); o.y = f2bf(v.y); o.z = f2bf(v.z); o.w = f2bf(v.w);
            *(ushort4*)(A + flat) = o;
        } else if (p < totalA + totalW) {
            int q = p - totalA;
            int flat = q * 4;
            int prow = flat / K_TOT;
            int col = flat - prow * K_TOT;
            int bn  = prow >> 8;
            int r   = prow & 255;
            int wcn = r >> 6;
            int g   = (r >> 4) & 3;
            int u   = r & 15;
            int j   = bn * 64 + wcn * 16 + u;
            const float* src;
            if (col < N_IN) {
                const float* Wx = (g == 0) ? Wii : (g == 1) ? Wif : (g == 2) ? Wig : Wio;
                src = Wx + (size_t)j * N_IN + col;
            } else {
                const float* Wh = (g == 0) ? Whi : (g == 1) ? Whf : (g == 2) ? Whg : Who;
                src = Wh + (size_t)j * N_HID + (col - N_IN);
            }
            float4 v = *(const float4*)src;
            ushort4 o;
            o.x = f2bf(v.x); o.y = f2bf(v.y); o.z = f2bf(v.z); o.w = f2bf(v.w);
            *(ushort4*)(Wp + flat) = o;
        } else {
            int n = p - totalA - totalW;
            int g = n >> 10, j = n & 1023;
            const float* bx = (g == 0) ? bii : (g == 1) ? bif : (g == 2) ? big : bio;
            const float* bh = (g == 0) ? bhi : (g == 1) ? bhf : (g == 2) ? bhg : bho;
            bias[n] = bx[j] + bh[j];
        }
    }
}

// ---------------- rotated-pipeline GEMM + LSTM epilogue -------------------
// R13 verified structure; single change this round: s_setprio REMOVED from
// the MFMA cluster. T5 is structure-conditional — it pays on phase-split
// schedules (m218b) but measured a real cost (−1.5%, m190 within-probe A/B)
// on lockstep GEMM structures like this one (all 8 waves barrier-synced per
// tile). It had been carried untested since R2.

__device__ __forceinline__ float sigmoid_f(float z) {
    return 1.f / (1.f + __expf(-z));
}
__device__ __forceinline__ float tanh_f(float z) {
    z = fminf(fmaxf(z, -15.f), 15.f);
    float e = __expf(2.f * z);
    return (e - 1.f) / (e + 1.f);
}

__global__ __launch_bounds__(512, 1) void lstm_gemm(
        const ushort* __restrict__ A, const ushort* __restrict__ W,
        const float* __restrict__ bias, const float* __restrict__ cin,
        float* __restrict__ outc, float* __restrict__ outh) {
    __shared__ ushort sA[4][256 * 32];   // 4 x 16 KB
    __shared__ ushort sB[4][256 * 32];   // 4 x 16 KB  (128 KB total)

    const int tid  = threadIdx.x;
    const int wid  = tid >> 6;
    const int lane = tid & 63;
    const int wr  = wid >> 2;    // 0..1  M half
    const int wcn = wid & 3;     // 0..3  N quarter (64 cols)
    const int m0 = blockIdx.x * 256;
    const int n0 = blockIdx.y * 256;

    f32x4 acc[8][4] = {};

    // staging map (validated): row = tid>>2, global chunk = (tid&3)^((tid>>3)&3)
    const int srow = tid >> 2;
    const int fch  = (tid & 3) ^ ((tid >> 3) & 3);
    const ushort* gA = A + (size_t)(m0 + srow) * K_TOT + fch * 8;
    const ushort* gB = W + (size_t)(n0 + srow) * K_TOT + fch * 8;

#define GLDS(gptr, lptr) __builtin_amdgcn_global_load_lds(                     \
        (const __attribute__((address_space(1))) void*)(gptr),                 \
        (__attribute__((address_space(3))) void*)(lptr), 16, 0, 0)

#define STAGE(db, kt) do {                                                     \
    GLDS(gA + (size_t)(kt) * 32,                  &sA[db][tid * 8]);           \
    GLDS(gA + (size_t)128 * K_TOT + (size_t)(kt) * 32, &sA[db][4096 + tid * 8]); \
    GLDS(gB + (size_t)(kt) * 32,                  &sB[db][tid * 8]);           \
    GLDS(gB + (size_t)128 * K_TOT + (size_t)(kt) * 32, &sB[db][4096 + tid * 8]); \
} while (0)

    const int lrow = lane & 15;
    const int cb0  = lane >> 4;             // 0..3 k-chunk
    const int csw2 = (lrow >> 1) & 3;       // read-side swizzle (0-conflict)
    const unsigned aByte = (unsigned)(((wr * 128 + lrow) * 32 + ((cb0 ^ csw2) * 8)) * 2);
    const unsigned bByte = (unsigned)(((wcn * 64  + lrow) * 32 + ((cb0 ^ csw2) * 8)) * 2);

#define DSR(dst, addr, IMM) asm volatile(                                      \
    "ds_read_b128 %0, %1 offset:" IMM : "=&v"(dst) : "v"(addr))

#define READS(afX, bfX, db) do {                                               \
    unsigned aAd = (unsigned)(uintptr_t)                                       \
        (__attribute__((address_space(3))) ushort*)&sA[db][0] + aByte;         \
    unsigned bAd = (unsigned)(uintptr_t)                                       \
        (__attribute__((address_space(3))) ushort*)&sB[db][0] + bByte;         \
    i32x4 r0, r1, r2, r3, r4, r5, r6, r7, s0, s1, s2, s3;                      \
    DSR(r0, aAd, "0");    DSR(r1, aAd, "1024");                                \
    DSR(r2, aAd, "2048"); DSR(r3, aAd, "3072");                                \
    DSR(r4, aAd, "4096"); DSR(r5, aAd, "5120");                                \
    DSR(r6, aAd, "6144"); DSR(r7, aAd, "7168");                                \
    DSR(s0, bAd, "0");    DSR(s1, bAd, "1024");                                \
    DSR(s2, bAd, "2048"); DSR(s3, bAd, "3072");                                \
    afX[0] = as_bf(r0); afX[1] = as_bf(r1); afX[2] = as_bf(r2);                \
    afX[3] = as_bf(r3); afX[4] = as_bf(r4); afX[5] = as_bf(r5);                \
    afX[6] = as_bf(r6); afX[7] = as_bf(r7);                                    \
    bfX[0] = as_bf(s0); bfX[1] = as_bf(s1); bfX[2] = as_bf(s2);                \
    bfX[3] = as_bf(s3);                                                        \
} while (0)

#define WAITK(n) do {                                                          \
    asm volatile("s_waitcnt lgkmcnt(" #n ")");                                 \
    __builtin_amdgcn_sched_barrier(0);                                         \
} while (0)

#define MFMAS(afX, bfX) do {                                                   \
    _Pragma("unroll")                                                          \
    for (int m = 0; m < 8; ++m)                                                \
        _Pragma("unroll")                                                      \
        for (int n = 0; n < 4; ++n)                                            \
            acc[m][n] = __builtin_amdgcn_mfma_f32_16x16x32_bf16(               \
                afX[m], bfX[n], acc[m][n], 0, 0, 0);                           \
} while (0)

#define BARX() __builtin_amdgcn_s_barrier()
#define VMC(n) asm volatile("s_waitcnt vmcnt(" #n ")" ::: "memory")

    bf16x8 af0[8], bfv0[4], af1[8], bfv1[4];

    // prologue: stage tiles 0,1,2; retire 0,1; read tile-0 frags
    STAGE(0, 0); STAGE(1, 1); STAGE(2, 2);
    VMC(4);
    BARX();
    READS(af0, bfv0, 0);

    // tile t: STAGE(t+3) | READS(t+1) | lgkm(12) | MFMA(t) | VMC(4) | BAR
#define TILE(u, t, Fna, Fnb, Fca, Fcb) do {                                    \
    STAGE(((u) + 3) & 3, (t) + 3);                                             \
    READS(Fna, Fnb, ((u) + 1) & 3);                                            \
    WAITK(12);                                                                 \
    MFMAS(Fca, Fcb);                                                           \
    VMC(4);                                                                    \
    BARX();                                                                    \
} while (0)

    for (int hh = 0; hh < 11; ++hh) {
        const int t = hh * 4;
        TILE(0, t + 0, af1, bfv1, af0, bfv0);
        TILE(1, t + 1, af0, bfv0, af1, bfv1);
        TILE(2, t + 2, af1, bfv1, af0, bfv0);
        TILE(3, t + 3, af0, bfv0, af1, bfv1);
    }
    // peeled tail: t = 44..47
    TILE(0, 44, af1, bfv1, af0, bfv0);          // stages 47
    // t=45: no stage; VMC(0) retires S47 before t=46 reads buf3
    READS(af0, bfv0, 2);                        // tile 46 frags
    WAITK(12);
    MFMAS(af1, bfv1);                           // tile 45
    VMC(0);
    BARX();
    // t=46
    READS(af1, bfv1, 3);                        // tile 47 frags
    WAITK(12);
    MFMAS(af0, bfv0);                           // tile 46
    BARX();
    // t=47
    WAITK(0);
    MFMAS(af1, bfv1);                           // tile 47

    // epilogue: lane owns unit = bn*64 + wcn*16 + lrow; gates = acc[m][0..3]
    const int unit = blockIdx.y * 64 + wcn * 16 + lrow;
    const float b0 = bias[unit];
    const float b1 = bias[1024 + unit];
    const float b2 = bias[2048 + unit];
    const float b3 = bias[3072 + unit];
    const int r0 = m0 + wr * 128 + (lane >> 4) * 4;
#pragma unroll
    for (int mi = 0; mi < 8; ++mi) {
#pragma unroll
        for (int q = 0; q < 4; ++q) {
            const int row = r0 + mi * 16 + q;
            const size_t off = (size_t)row * N_HID + unit;
            float zi = acc[mi][0][q] + b0;
            float zf = acc[mi][1][q] + b1;
            float zg = acc[mi][2][q] + b2;
            float zo = acc[mi][3][q] + b3;
            float it_ = sigmoid_f(zi);
            float ft = sigmoid_f(zf);
            float gt = tanh_f(zg);
            float ot = sigmoid_f(zo);
            float ct = ft * cin[off] + it_ * gt;
            float ht = ot * tanh_f(ct);
            outc[off] = ct;
            outh[off] = ht;
        }
    }
#undef GLDS
#undef STAGE
#undef DSR
#undef READS
#undef WAITK
#undef MFMAS
#undef BARX
#undef VMC
#undef TILE
}

// ---------------- launch ----------------

extern "C" void kernel_launch(void* const* d_in, const int* in_sizes, int n_in,
                              void* d_out, int out_size, void* d_ws, size_t ws_size,
                              hipStream_t stream) {
    const float* x = (const float*)d_in[0];
    const float* c = (const float*)d_in[1];
    const float* h = (const float*)d_in[2];
    const float* Wii = (const float*)d_in[3];  const float* bii = (const float*)d_in[4];
    const float* Wif = (const float*)d_in[5];  const float* bif = (const float*)d_in[6];
    const float* Wig = (const float*)d_in[7];  const float* big = (const float*)d_in[8];
    const float* Wio = (const float*)d_in[9];  const float* bio = (const float*)d_in[10];
    const float* Whi = (const float*)d_in[11]; const float* bhi = (const float*)d_in[12];
    const float* Whf = (const float*)d_in[13]; const float* bhf = (const float*)d_in[14];
    const float* Whg = (const float*)d_in[15]; const float* bhg = (const float*)d_in[16];
    const float* Who = (const float*)d_in[17]; const float* bho = (const float*)d_in[18];

    char* ws = (char*)d_ws;
    ushort* A_cat  = (ushort*)ws;                                   // 50,331,648 B
    ushort* W_perm = (ushort*)(ws + (size_t)M_ROWS * K_TOT * 2);    // 12,582,912 B
    float*  biasc  = (float*)(ws + (size_t)M_ROWS * K_TOT * 2
                                 + (size_t)N_TOT * K_TOT * 2);      // 16 KB

    float* outc = (float*)d_out;
    float* outh = (float*)d_out + (size_t)M_ROWS * N_HID;

    hipLaunchKernelGGL(prep_all, dim3(2048), dim3(256), 0, stream,
                       x, h,
                       Wii, Wif, Wig, Wio, Whi, Whf, Whg, Who,
                       bii, bif, big, bio, bhi, bhf, bhg, bho,
                       A_cat, W_perm, biasc);
    hipLaunchKernelGGL(lstm_gemm, dim3(M_ROWS / 256, N_TOT / 256), dim3(512), 0, stream,
                       A_cat, W_perm, biasc, c, outc, outh);
}

// Round 19
// 271.320 us; speedup vs baseline: 1.0125x; 1.0002x over previous
//
#include <hip/hip_runtime.h>
#include <hip/hip_bf16.h>

#define M_ROWS 16384
#define N_IN   512
#define N_HID  1024
#define K_TOT  1536   // 512 + 1024
#define N_TOT  4096   // 4 gates * 1024
#define NT     48     // K tiles of BK=32

typedef __attribute__((ext_vector_type(4))) float f32x4;
typedef __attribute__((ext_vector_type(8))) short bf16x8;
typedef __attribute__((ext_vector_type(4))) int   i32x4;

__device__ __forceinline__ ushort f2bf(float f) {
    union { float f; unsigned u; } un; un.f = f;
    unsigned u = un.u;
    u += 0x7fffu + ((u >> 16) & 1u);   // RNE
    return (ushort)(u >> 16);
}

__device__ __forceinline__ bf16x8 as_bf(i32x4 v) {
    union { i32x4 i; bf16x8 b; } u; u.i = v; return u.b;
}

// ---------------- fused prep kernel (R12, validated) ----------------

__global__ void prep_all(const float* __restrict__ x, const float* __restrict__ h,
                         const float* __restrict__ Wii, const float* __restrict__ Wif,
                         const float* __restrict__ Wig, const float* __restrict__ Wio,
                         const float* __restrict__ Whi, const float* __restrict__ Whf,
                         const float* __restrict__ Whg, const float* __restrict__ Who,
                         const float* __restrict__ bii, const float* __restrict__ bif,
                         const float* __restrict__ big, const float* __restrict__ bio,
                         const float* __restrict__ bhi, const float* __restrict__ bhf,
                         const float* __restrict__ bhg, const float* __restrict__ bho,
                         ushort* __restrict__ A, ushort* __restrict__ Wp,
                         float* __restrict__ bias) {
    const int totalA = M_ROWS * K_TOT / 4;   // 6,291,456
    const int totalW = N_TOT * K_TOT / 4;    // 1,572,864
    const int totalE = totalA + totalW + N_TOT;
    const int stride = gridDim.x * blockDim.x;
    for (int p = blockIdx.x * blockDim.x + threadIdx.x; p < totalE; p += stride) {
        if (p < totalA) {
            int flat = p * 4;
            int row = flat / K_TOT;
            int col = flat - row * K_TOT;
            const float* src = (col < N_IN)
                ? (x + (size_t)row * N_IN + col)
                : (h + (size_t)row * N_HID + (col - N_IN));
            float4 v = *(const float4*)src;
            ushort4 o;
            o.x = f2bf(v.x); o.y = f2bf(v.y); o.z = f2bf(v.z); o.w = f2bf(v.w);
            *(ushort4*)(A + flat) = o;
        } else if (p < totalA + totalW) {
            int q = p - totalA;
            int flat = q * 4;
            int prow = flat / K_TOT;
            int col = flat - prow * K_TOT;
            int bn  = prow >> 8;
            int r   = prow & 255;
            int wcn = r >> 6;
            int g   = (r >> 4) & 3;
            int u   = r & 15;
            int j   = bn * 64 + wcn * 16 + u;
            const float* src;
            if (col < N_IN) {
                const float* Wx = (g == 0) ? Wii : (g == 1) ? Wif : (g == 2) ? Wig : Wio;
                src = Wx + (size_t)j * N_IN + col;
            } else {
                const float* Wh = (g == 0) ? Whi : (g == 1) ? Whf : (g == 2) ? Whg : Who;
                src = Wh + (size_t)j * N_HID + (col - N_IN);
            }
            float4 v = *(const float4*)src;
            ushort4 o;
            o.x = f2bf(v.x); o.y = f2bf(v.y); o.z = f2bf(v.z); o.w = f2bf(v.w);
            *(ushort4*)(Wp + flat) = o;
        } else {
            int n = p - totalA - totalW;
            int g = n >> 10, j = n & 1023;
            const float* bx = (g == 0) ? bii : (g == 1) ? bif : (g == 2) ? big : bio;
            const float* bh = (g == 0) ? bhi : (g == 1) ? bhf : (g == 2) ? bhg : bho;
            bias[n] = bx[j] + bh[j];
        }
    }
}

// ---------------- rotated-pipeline GEMM + LSTM epilogue (FINAL) -----------
// 256x256 block, BK=32, 48 K-tiles, 8 waves (2M x 4N), per-wave 128x64.
// 4 LDS buffers; register rotate (frags for t+1 ds_read during t via asm
// ds_read_b128 + counted lgkmcnt(12) + sched_barrier); intrinsic
// global_load_lds staging, stage-ahead-3, VMC(4) retires buf(t+2) one tile
// before its reads; no setprio (negative on lockstep structures, R18 A/B).
// Session result: 9 schedule structures all land 744-838 TF / 33-37%
// MfmaUtil (the documented 2-phase-class structural ceiling); co-residency
// is register- (256-tile) or traffic- (128-tile) infeasible; fp8 fails the
// error budget. Best verified composition: ~271 us total.

__device__ __forceinline__ float sigmoid_f(float z) {
    return 1.f / (1.f + __expf(-z));
}
__device__ __forceinline__ float tanh_f(float z) {
    z = fminf(fmaxf(z, -15.f), 15.f);
    float e = __expf(2.f * z);
    return (e - 1.f) / (e + 1.f);
}

__global__ __launch_bounds__(512, 1) void lstm_gemm(
        const ushort* __restrict__ A, const ushort* __restrict__ W,
        const float* __restrict__ bias, const float* __restrict__ cin,
        float* __restrict__ outc, float* __restrict__ outh) {
    __shared__ ushort sA[4][256 * 32];   // 4 x 16 KB
    __shared__ ushort sB[4][256 * 32];   // 4 x 16 KB  (128 KB total)

    const int tid  = threadIdx.x;
    const int wid  = tid >> 6;
    const int lane = tid & 63;
    const int wr  = wid >> 2;    // 0..1  M half
    const int wcn = wid & 3;     // 0..3  N quarter (64 cols)
    const int m0 = blockIdx.x * 256;
    const int n0 = blockIdx.y * 256;

    f32x4 acc[8][4] = {};

    // staging map (validated): row = tid>>2, global chunk = (tid&3)^((tid>>3)&3)
    const int srow = tid >> 2;
    const int fch  = (tid & 3) ^ ((tid >> 3) & 3);
    const ushort* gA = A + (size_t)(m0 + srow) * K_TOT + fch * 8;
    const ushort* gB = W + (size_t)(n0 + srow) * K_TOT + fch * 8;

#define GLDS(gptr, lptr) __builtin_amdgcn_global_load_lds(                     \
        (const __attribute__((address_space(1))) void*)(gptr),                 \
        (__attribute__((address_space(3))) void*)(lptr), 16, 0, 0)

#define STAGE(db, kt) do {                                                     \
    GLDS(gA + (size_t)(kt) * 32,                  &sA[db][tid * 8]);           \
    GLDS(gA + (size_t)128 * K_TOT + (size_t)(kt) * 32, &sA[db][4096 + tid * 8]); \
    GLDS(gB + (size_t)(kt) * 32,                  &sB[db][tid * 8]);           \
    GLDS(gB + (size_t)128 * K_TOT + (size_t)(kt) * 32, &sB[db][4096 + tid * 8]); \
} while (0)

    const int lrow = lane & 15;
    const int cb0  = lane >> 4;             // 0..3 k-chunk
    const int csw2 = (lrow >> 1) & 3;       // read-side swizzle (0-conflict)
    const unsigned aByte = (unsigned)(((wr * 128 + lrow) * 32 + ((cb0 ^ csw2) * 8)) * 2);
    const unsigned bByte = (unsigned)(((wcn * 64  + lrow) * 32 + ((cb0 ^ csw2) * 8)) * 2);

#define DSR(dst, addr, IMM) asm volatile(                                      \
    "ds_read_b128 %0, %1 offset:" IMM : "=&v"(dst) : "v"(addr))

#define READS(afX, bfX, db) do {                                               \
    unsigned aAd = (unsigned)(uintptr_t)                                       \
        (__attribute__((address_space(3))) ushort*)&sA[db][0] + aByte;         \
    unsigned bAd = (unsigned)(uintptr_t)                                       \
        (__attribute__((address_space(3))) ushort*)&sB[db][0] + bByte;         \
    i32x4 r0, r1, r2, r3, r4, r5, r6, r7, s0, s1, s2, s3;                      \
    DSR(r0, aAd, "0");    DSR(r1, aAd, "1024");                                \
    DSR(r2, aAd, "2048"); DSR(r3, aAd, "3072");                                \
    DSR(r4, aAd, "4096"); DSR(r5, aAd, "5120");                                \
    DSR(r6, aAd, "6144"); DSR(r7, aAd, "7168");                                \
    DSR(s0, bAd, "0");    DSR(s1, bAd, "1024");                                \
    DSR(s2, bAd, "2048"); DSR(s3, bAd, "3072");                                \
    afX[0] = as_bf(r0); afX[1] = as_bf(r1); afX[2] = as_bf(r2);                \
    afX[3] = as_bf(r3); afX[4] = as_bf(r4); afX[5] = as_bf(r5);                \
    afX[6] = as_bf(r6); afX[7] = as_bf(r7);                                    \
    bfX[0] = as_bf(s0); bfX[1] = as_bf(s1); bfX[2] = as_bf(s2);                \
    bfX[3] = as_bf(s3);                                                        \
} while (0)

#define WAITK(n) do {                                                          \
    asm volatile("s_waitcnt lgkmcnt(" #n ")");                                 \
    __builtin_amdgcn_sched_barrier(0);                                         \
} while (0)

#define MFMAS(afX, bfX) do {                                                   \
    _Pragma("unroll")                                                          \
    for (int m = 0; m < 8; ++m)                                                \
        _Pragma("unroll")                                                      \
        for (int n = 0; n < 4; ++n)                                            \
            acc[m][n] = __builtin_amdgcn_mfma_f32_16x16x32_bf16(               \
                afX[m], bfX[n], acc[m][n], 0, 0, 0);                           \
} while (0)

#define BARX() __builtin_amdgcn_s_barrier()
#define VMC(n) asm volatile("s_waitcnt vmcnt(" #n ")" ::: "memory")

    bf16x8 af0[8], bfv0[4], af1[8], bfv1[4];

    // prologue: stage tiles 0,1,2; retire 0,1; read tile-0 frags
    STAGE(0, 0); STAGE(1, 1); STAGE(2, 2);
    VMC(4);
    BARX();
    READS(af0, bfv0, 0);

    // tile t: STAGE(t+3) | READS(t+1) | lgkm(12) | MFMA(t) | VMC(4) | BAR
#define TILE(u, t, Fna, Fnb, Fca, Fcb) do {                                    \
    STAGE(((u) + 3) & 3, (t) + 3);                                             \
    READS(Fna, Fnb, ((u) + 1) & 3);                                            \
    WAITK(12);                                                                 \
    MFMAS(Fca, Fcb);                                                           \
    VMC(4);                                                                    \
    BARX();                                                                    \
} while (0)

    for (int hh = 0; hh < 11; ++hh) {
        const int t = hh * 4;
        TILE(0, t + 0, af1, bfv1, af0, bfv0);
        TILE(1, t + 1, af0, bfv0, af1, bfv1);
        TILE(2, t + 2, af1, bfv1, af0, bfv0);
        TILE(3, t + 3, af0, bfv0, af1, bfv1);
    }
    // peeled tail: t = 44..47
    TILE(0, 44, af1, bfv1, af0, bfv0);          // stages 47
    // t=45: no stage; VMC(0) retires S47 before t=46 reads buf3
    READS(af0, bfv0, 2);                        // tile 46 frags
    WAITK(12);
    MFMAS(af1, bfv1);                           // tile 45
    VMC(0);
    BARX();
    // t=46
    READS(af1, bfv1, 3);                        // tile 47 frags
    WAITK(12);
    MFMAS(af0, bfv0);                           // tile 46
    BARX();
    // t=47
    WAITK(0);
    MFMAS(af1, bfv1);                           // tile 47

    // epilogue: lane owns unit = bn*64 + wcn*16 + lrow; gates = acc[m][0..3]
    const int unit = blockIdx.y * 64 + wcn * 16 + lrow;
    const float b0 = bias[unit];
    const float b1 = bias[1024 + unit];
    const float b2 = bias[2048 + unit];
    const float b3 = bias[3072 + unit];
    const int r0 = m0 + wr * 128 + (lane >> 4) * 4;
#pragma unroll
    for (int mi = 0; mi < 8; ++mi) {
#pragma unroll
        for (int q = 0; q < 4; ++q) {
            const int row = r0 + mi * 16 + q;
            const size_t off = (size_t)row * N_HID + unit;
            float zi = acc[mi][0][q] + b0;
            float zf = acc[mi][1][q] + b1;
            float zg = acc[mi][2][q] + b2;
            float zo = acc[mi][3][q] + b3;
            float it_ = sigmoid_f(zi);
            float ft = sigmoid_f(zf);
            float gt = tanh_f(zg);
            float ot = sigmoid_f(zo);
            float ct = ft * cin[off] + it_ * gt;
            float ht = ot * tanh_f(ct);
            outc[off] = ct;
            outh[off] = ht;
        }
    }
#undef GLDS
#undef STAGE
#undef DSR
#undef READS
#undef WAITK
#undef MFMAS
#undef BARX
#undef VMC
#undef TILE
}

// ---------------- launch ----------------

extern "C" void kernel_launch(void* const* d_in, const int* in_sizes, int n_in,
                              void* d_out, int out_size, void* d_ws, size_t ws_size,
                              hipStream_t stream) {
    const float* x = (const float*)d_in[0];
    const float* c = (const float*)d_in[1];
    const float* h = (const float*)d_in[2];
    const float* Wii = (const float*)d_in[3];  const float* bii = (const float*)d_in[4];
    const float* Wif = (const float*)d_in[5];  const float* bif = (const float*)d_in[6];
    const float* Wig = (const float*)d_in[7];  const float* big = (const float*)d_in[8];
    const float* Wio = (const float*)d_in[9];  const float* bio = (const float*)d_in[10];
    const float* Whi = (const float*)d_in[11]; const float* bhi = (const float*)d_in[12];
    const float* Whf = (const float*)d_in[13]; const float* bhf = (const float*)d_in[14];
    const float* Whg = (const float*)d_in[15]; const float* bhg = (const float*)d_in[16];
    const float* Who = (const float*)d_in[17]; const float* bho = (const float*)d_in[18];

    char* ws = (char*)d_ws;
    ushort* A_cat  = (ushort*)ws;                                   // 50,331,648 B
    ushort* W_perm = (ushort*)(ws + (size_t)M_ROWS * K_TOT * 2);    // 12,582,912 B
    float*  biasc  = (float*)(ws + (size_t)M_ROWS * K_TOT * 2
                                 + (size_t)N_TOT * K_TOT * 2);      // 16 KB

    float* outc = (float*)d_out;
    float* outh = (float*)d_out + (size_t)M_ROWS * N_HID;

    hipLaunchKernelGGL(prep_all, dim3(2048), dim3(256), 0, stream,
                       x, h,
                       Wii, Wif, Wig, Wio, Whi, Whf, Whg, Who,
                       bii, bif, big, bio, bhi, bhf, bhg, bho,
                       A_cat, W_perm, biasc);
    hipLaunchKernelGGL(lstm_gemm, dim3(M_ROWS / 256, N_TOT / 256), dim3(512), 0, stream,
                       A_cat, W_perm, biasc, c, outc, outh);
}